// Round 4
// baseline (101.115 us; speedup 1.0000x reference)
//
#include <hip/hip_runtime.h>
#include <hip/hip_bf16.h>
#include <math.h>

#define FDIM  128
#define BATCH 4096
#define CNUM  10000

typedef __attribute__((ext_vector_type(8))) short short8;   // 8 bf16 = 4 VGPRs (MFMA A/B frag)
typedef __attribute__((ext_vector_type(4))) float f32x4;    // MFMA C/D frag / float4 store

// ---------------- ws layout (bytes) ----------------
#define WS_FEATB 0            // 4096*128 bf16  = 1048576
#define WS_WB    1048576      // 10000*128 bf16 = 2560000
#define WS_F2    3608576      // 4096 f32
#define WS_W2    3624960      // 10000 f32
#define WS_COR   3664960      // 4096 f32
#define WS_LS2   3681344      // 1 f32 (log2 of scale)

// exp(-m/1.8) = 2^(-m * C2);  C2 = 1/(1.8*ln2)
#define C2 0.80178372573096f

// Kernel 1: fused prep (f32->bf16 convert + row norms) and cor gather.
__global__ void prep_cor_kernel(const float* __restrict__ feat,
                                const float* __restrict__ weights,
                                const int* __restrict__ label,
                                __hip_bfloat16* __restrict__ featb,
                                __hip_bfloat16* __restrict__ wb,
                                float* __restrict__ f2,
                                float* __restrict__ w2,
                                float* __restrict__ cor) {
    int gw   = (blockIdx.x * blockDim.x + threadIdx.x) >> 6;
    int lane = threadIdx.x & 63;
    if (gw < BATCH + CNUM) {
        const float* src;
        __hip_bfloat16* dst;
        float* nrm;
        if (gw < BATCH) { src = feat    + (size_t)gw * FDIM; dst = featb + (size_t)gw * FDIM; nrm = f2 + gw; }
        else            { int r = gw - BATCH;
                          src = weights + (size_t)r  * FDIM; dst = wb    + (size_t)r  * FDIM; nrm = w2 + r; }
        float2 v = ((const float2*)src)[lane];
        __hip_bfloat162 b2;
        b2.x = __float2bfloat16(v.x);
        b2.y = __float2bfloat16(v.y);
        ((__hip_bfloat162*)dst)[lane] = b2;
        float ss = v.x * v.x + v.y * v.y;
        #pragma unroll
        for (int off = 32; off; off >>= 1) ss += __shfl_down(ss, off, 64);
        if (lane == 0) *nrm = ss;
    } else {
        int s = gw - (BATCH + CNUM);
        if (s >= BATCH) return;
        int lab = label[s];
        float2 f = ((const float2*)(feat    + (size_t)s   * FDIM))[lane];
        float2 w = ((const float2*)(weights + (size_t)lab * FDIM))[lane];
        float dx = f.x - w.x, dy = f.y - w.y;
        float ss = dx * dx + dy * dy;
        #pragma unroll
        for (int off = 32; off; off >>= 1) ss += __shfl_down(ss, off, 64);
        if (lane == 0) cor[s] = __expf(-ss * (1.0f / 1.8f));
    }
}

// Kernel 2: deterministic reduction of cor -> ls2 = log2(log(C-1)/max(mean,0.5)).
__global__ void scale_kernel(const float* __restrict__ cor, float* __restrict__ ls2) {
    __shared__ float red[4];
    int t = threadIdx.x;
    float s = 0.0f;
    #pragma unroll
    for (int i = 0; i < BATCH / 256; i++) s += cor[t + i * 256];
    #pragma unroll
    for (int off = 32; off; off >>= 1) s += __shfl_down(s, off, 64);
    if ((t & 63) == 0) red[t >> 6] = s;
    __syncthreads();
    if (t == 0) {
        float avg = (red[0] + red[1] + red[2] + red[3]) * (1.0f / BATCH);
        avg = fmaxf(avg, 0.5f);
        *ls2 = log2f(logf((float)(CNUM - 1)) / avg);
    }
}

// Kernel 3: persistent-sweep GEMM + fused epilogue.
// Grid = 1024 blocks, all resident (4/CU). Block = 4 waves.
// Block owns: 16 batch rows (band) x 2560 classes (quarter), sweeping 10
// class-tiles of 256 (wave w takes classes [t*256+w*64, +64) x all 16 rows).
// A = wb (classes = M, 4 frags), B = featb (batch = N, 1 frag, HOISTED for
// the whole kernel: loop-invariant). f2 hoisted. Per iter: 16 wb loads,
// 16 MFMA, 16-elem epilogue, 4 dwordx4 stores.
// C/D: col=lane&15 -> batch row, row=kh*4+reg -> class => lane f32x4 = 4
// consecutive classes of one output row. Per-row writes are time-sequential
// across the sweep -> 10 KB contiguous DRAM streams per row.
__launch_bounds__(256, 4)
__global__ void gemm_kernel(const __hip_bfloat16* __restrict__ featb,
                            const __hip_bfloat16* __restrict__ wb,
                            const float* __restrict__ f2,
                            const float* __restrict__ w2,
                            const float* __restrict__ ls2_p,
                            float* __restrict__ out) {
    int band = blockIdx.x & 255;          // 256 row-bands of 16 rows
    int q    = blockIdx.x >> 8;           // 4 class quarters (10 tiles of 256 each)
    int tid  = threadIdx.x;
    int wid  = tid >> 6;
    int lane = tid & 63;
    int r16  = lane & 15;                  // batch row within band
    int kh   = lane >> 4;                  // k-chunk / class sub-offset group
    float ls2 = *ls2_p;

    int row = band * 16 + r16;             // this lane's batch row (all stores here)
    float f2n = f2[row];
    const short* A = (const short*)wb;     // classes
    const short* B = (const short*)featb;  // batch

    // hoist the batch (B) fragments for the whole sweep: K=128 -> 4 chunks
    short8 b[4];
    #pragma unroll
    for (int kk = 0; kk < 4; kk++)
        b[kk] = *(const short8*)(B + (size_t)row * FDIM + kk * 32 + kh * 8);

    float* outrow = out + (size_t)row * CNUM;

    int t0 = q * 10;
    for (int t = t0; t < t0 + 10; ++t) {
        int mbase = t * 256 + wid * 64;    // this wave's 64-class chunk

        f32x4 acc[4];
        #pragma unroll
        for (int m = 0; m < 4; m++) acc[m] = (f32x4){0.f, 0.f, 0.f, 0.f};

        #pragma unroll
        for (int kk = 0; kk < 4; kk++) {
            short8 a[4];
            #pragma unroll
            for (int m = 0; m < 4; m++) {
                int cr = mbase + m * 16 + r16;
                cr = cr < CNUM ? cr : CNUM - 1;   // clamp reads; stores masked below
                a[m] = *(const short8*)(A + (size_t)cr * FDIM + kk * 32 + kh * 8);
            }
            #pragma unroll
            for (int m = 0; m < 4; m++)
                acc[m] = __builtin_amdgcn_mfma_f32_16x16x32_bf16(a[m], b[kk], acc[m], 0, 0, 0);
        }

        #pragma unroll
        for (int m = 0; m < 4; m++) {
            int cm0 = mbase + m * 16 + kh * 4;    // first of 4 consecutive classes
            if (cm0 < CNUM) {                      // cm0,CNUM % 4 == 0 -> no straddle
                f32x4 w4 = *(const f32x4*)(w2 + cm0);
                f32x4 v;
                #pragma unroll
                for (int r = 0; r < 4; r++) {
                    float m2 = fmaf(-2.0f, acc[m][r], f2n + w4[r]);
                    m2 = fmaxf(m2, 0.0f);
                    v[r] = exp2f(fmaf(m2, -C2, ls2));
                }
                *(f32x4*)(outrow + cm0) = v;
            }
        }
    }
}

extern "C" void kernel_launch(void* const* d_in, const int* in_sizes, int n_in,
                              void* d_out, int out_size, void* d_ws, size_t ws_size,
                              hipStream_t stream) {
    (void)in_sizes; (void)n_in; (void)out_size; (void)ws_size;
    const float* feat    = (const float*)d_in[0];
    const float* weights = (const float*)d_in[1];
    const int*   label   = (const int*)d_in[2];
    float* out = (float*)d_out;
    char*  ws  = (char*)d_ws;

    __hip_bfloat16* featb = (__hip_bfloat16*)(ws + WS_FEATB);
    __hip_bfloat16* wb    = (__hip_bfloat16*)(ws + WS_WB);
    float* f2  = (float*)(ws + WS_F2);
    float* w2  = (float*)(ws + WS_W2);
    float* cor = (float*)(ws + WS_COR);
    float* ls2 = (float*)(ws + WS_LS2);

    const int total_waves = BATCH + CNUM + BATCH;
    prep_cor_kernel<<<(total_waves + 3) / 4, 256, 0, stream>>>(
        feat, weights, label, featb, wb, f2, w2, cor);
    scale_kernel<<<1, 256, 0, stream>>>(cor, ls2);

    gemm_kernel<<<1024, 256, 0, stream>>>(featb, wb, f2, w2, ls2, out);
}

// Round 5
// 61.062 us; speedup vs baseline: 1.6559x; 1.6559x over previous
//
#include <hip/hip_runtime.h>
#include <hip/hip_bf16.h>
#include <math.h>

#define FDIM  128
#define BATCH 4096
#define CNUM  10000

typedef __attribute__((ext_vector_type(8))) short short8;   // 8 bf16 = 4 VGPRs (MFMA A/B frag)
typedef __attribute__((ext_vector_type(4))) float f32x4;    // MFMA C/D frag / float4 store

// ---------------- ws layout (bytes) ----------------
#define WS_FEATB 0            // 4096*128 bf16  = 1048576
#define WS_WB    1048576      // 10000*128 bf16 = 2560000
#define WS_F2    3608576      // 4096 f32
#define WS_W2    3624960      // 10000 f32
#define WS_COR   3664960      // 4096 f32
#define WS_LS2   3681344      // 1 f32 (log2 of scale)

// exp(-m/1.8) = 2^(-m * C2);  C2 = 1/(1.8*ln2)
#define C2 0.80178372573096f

// async global->LDS, 16B per lane, literal size
#define GL2LDS(g, l) __builtin_amdgcn_global_load_lds(                      \
    (const __attribute__((address_space(1))) void*)(g),                     \
    (__attribute__((address_space(3))) void*)(l), 16, 0, 0)

// Kernel 1: fused prep (f32->bf16 convert + row norms) and cor gather.
__global__ void prep_cor_kernel(const float* __restrict__ feat,
                                const float* __restrict__ weights,
                                const int* __restrict__ label,
                                __hip_bfloat16* __restrict__ featb,
                                __hip_bfloat16* __restrict__ wb,
                                float* __restrict__ f2,
                                float* __restrict__ w2,
                                float* __restrict__ cor) {
    int gw   = (blockIdx.x * blockDim.x + threadIdx.x) >> 6;
    int lane = threadIdx.x & 63;
    if (gw < BATCH + CNUM) {
        const float* src;
        __hip_bfloat16* dst;
        float* nrm;
        if (gw < BATCH) { src = feat    + (size_t)gw * FDIM; dst = featb + (size_t)gw * FDIM; nrm = f2 + gw; }
        else            { int r = gw - BATCH;
                          src = weights + (size_t)r  * FDIM; dst = wb    + (size_t)r  * FDIM; nrm = w2 + r; }
        float2 v = ((const float2*)src)[lane];
        __hip_bfloat162 b2;
        b2.x = __float2bfloat16(v.x);
        b2.y = __float2bfloat16(v.y);
        ((__hip_bfloat162*)dst)[lane] = b2;
        float ss = v.x * v.x + v.y * v.y;
        #pragma unroll
        for (int off = 32; off; off >>= 1) ss += __shfl_down(ss, off, 64);
        if (lane == 0) *nrm = ss;
    } else {
        int s = gw - (BATCH + CNUM);
        if (s >= BATCH) return;
        int lab = label[s];
        float2 f = ((const float2*)(feat    + (size_t)s   * FDIM))[lane];
        float2 w = ((const float2*)(weights + (size_t)lab * FDIM))[lane];
        float dx = f.x - w.x, dy = f.y - w.y;
        float ss = dx * dx + dy * dy;
        #pragma unroll
        for (int off = 32; off; off >>= 1) ss += __shfl_down(ss, off, 64);
        if (lane == 0) cor[s] = __expf(-ss * (1.0f / 1.8f));
    }
}

// Kernel 2: deterministic reduction of cor -> ls2 = log2(log(C-1)/max(mean,0.5)).
__global__ void scale_kernel(const float* __restrict__ cor, float* __restrict__ ls2) {
    __shared__ float red[4];
    int t = threadIdx.x;
    float s = 0.0f;
    #pragma unroll
    for (int i = 0; i < BATCH / 256; i++) s += cor[t + i * 256];
    #pragma unroll
    for (int off = 32; off; off >>= 1) s += __shfl_down(s, off, 64);
    if ((t & 63) == 0) red[t >> 6] = s;
    __syncthreads();
    if (t == 0) {
        float avg = (red[0] + red[1] + red[2] + red[3]) * (1.0f / BATCH);
        avg = fmaxf(avg, 0.5f);
        *ls2 = log2f(logf((float)(CNUM - 1)) / avg);
    }
}

// Kernel 3: LDS-staged GEMM + fused epilogue (m97-style, single K-pass).
// Block = 256 threads / 4 waves, tile 128 classes x 128 batch, K=128 one shot.
// A = wb (classes), B = featb (batch), both staged 32KB into LDS via
// global_load_lds (16B/lane, coalesced). LDS row = 256B; chunk index is
// XOR-swizzled (chunk ^= row&7) via PRE-SWIZZLED GLOBAL SOURCE (linear LDS
// dest, rule #21) and the same XOR on ds_read -> 16-way bank conflict -> 2-way.
// Wave = 64x64: acc[4][4]. C/D: col=lane&15 -> batch row, row=kh*4+reg ->
// class => lane f32x4 = 4 consecutive classes -> dwordx4 stores.
__launch_bounds__(256, 2)
__global__ void gemm_kernel(const __hip_bfloat16* __restrict__ featb,
                            const __hip_bfloat16* __restrict__ wb,
                            const float* __restrict__ f2,
                            const float* __restrict__ w2,
                            const float* __restrict__ ls2_p,
                            float* __restrict__ out) {
    __shared__ __align__(16) char ldsbuf[65536];
    char* ldsA = ldsbuf;            // 128 x 256B, chunk-swizzled
    char* ldsB = ldsbuf + 32768;

    const int MT = (CNUM + 127) / 128;   // 79 class tiles (last partial: 16)
    int mt = blockIdx.x % MT;
    int nt = blockIdx.x / MT;            // 32 batch tiles
    int tid  = threadIdx.x;
    int wid  = tid >> 6;
    int lane = tid & 63;
    int r16  = lane & 15;
    int kh   = lane >> 4;
    float ls2 = *ls2_p;

    // ---- stage both tiles: 8 x 4KB per tile, 16B per lane ----
    {
        int srow = tid >> 4;            // 0..15
        int schk = tid & 15;            // 16B chunk within the 256B row
        const char* Ab = (const char*)wb;
        const char* Bb = (const char*)featb;
        #pragma unroll
        for (int g = 0; g < 8; ++g) {
            int row  = g * 16 + srow;               // 0..127
            int gchk = schk ^ (row & 7);            // pre-swizzled source chunk
            int ga = mt * 128 + row; ga = ga < CNUM ? ga : CNUM - 1;  // clamp reads
            int gb = nt * 128 + row;
            GL2LDS(Ab + (size_t)ga * 256 + gchk * 16, ldsA + g * 4096 + tid * 16);
            GL2LDS(Bb + (size_t)gb * 256 + gchk * 16, ldsB + g * 4096 + tid * 16);
        }
    }
    __syncthreads();   // compiler drains vmcnt before the barrier

    int aoff = (wid >> 1) * 64;          // class half within tile
    int boff = (wid & 1) * 64;           // batch half within tile

    f32x4 acc[4][4];
    #pragma unroll
    for (int m = 0; m < 4; ++m)
        #pragma unroll
        for (int n = 0; n < 4; ++n) acc[m][n] = (f32x4){0.f, 0.f, 0.f, 0.f};

    #pragma unroll
    for (int kk = 0; kk < 4; ++kk) {
        short8 a[4], b[4];
        #pragma unroll
        for (int m = 0; m < 4; ++m) {
            int r = aoff + m * 16 + r16;
            int c = (kk * 4 + kh) ^ (r & 7);         // swizzled read chunk
            a[m] = *(const short8*)(ldsA + r * 256 + c * 16);
        }
        #pragma unroll
        for (int n = 0; n < 4; ++n) {
            int r = boff + n * 16 + r16;
            int c = (kk * 4 + kh) ^ (r & 7);
            b[n] = *(const short8*)(ldsB + r * 256 + c * 16);
        }
        #pragma unroll
        for (int m = 0; m < 4; ++m)
            #pragma unroll
            for (int n = 0; n < 4; ++n)
                acc[m][n] = __builtin_amdgcn_mfma_f32_16x16x32_bf16(a[m], b[n], acc[m][n], 0, 0, 0);
    }

    // ---- epilogue: out = 2^(ls2 - relu(f2+w2-2d)*C2), dwordx4 stores ----
    int mbase = mt * 128 + aoff;
    int nbase = nt * 128 + boff;
    float f2n[4];
    #pragma unroll
    for (int n = 0; n < 4; ++n) f2n[n] = f2[nbase + n * 16 + r16];

    #pragma unroll
    for (int m = 0; m < 4; ++m) {
        int cm0 = mbase + m * 16 + kh * 4;      // first of 4 consecutive classes
        bool ok = cm0 < CNUM;                    // cm0,CNUM % 4 == 0 -> no straddle
        f32x4 w4 = *(const f32x4*)(w2 + (ok ? cm0 : 0));
        #pragma unroll
        for (int n = 0; n < 4; ++n) {
            f32x4 v;
            #pragma unroll
            for (int r = 0; r < 4; ++r) {
                float t = fmaf(-2.0f, acc[m][n][r], f2n[n] + w4[r]);
                t = fmaxf(t, 0.0f);
                v[r] = exp2f(fmaf(t, -C2, ls2));
            }
            if (ok) {
                size_t bn = (size_t)(nbase + n * 16 + r16);
                *(f32x4*)(out + bn * CNUM + cm0) = v;
            }
        }
    }
}

extern "C" void kernel_launch(void* const* d_in, const int* in_sizes, int n_in,
                              void* d_out, int out_size, void* d_ws, size_t ws_size,
                              hipStream_t stream) {
    (void)in_sizes; (void)n_in; (void)out_size; (void)ws_size;
    const float* feat    = (const float*)d_in[0];
    const float* weights = (const float*)d_in[1];
    const int*   label   = (const int*)d_in[2];
    float* out = (float*)d_out;
    char*  ws  = (char*)d_ws;

    __hip_bfloat16* featb = (__hip_bfloat16*)(ws + WS_FEATB);
    __hip_bfloat16* wb    = (__hip_bfloat16*)(ws + WS_WB);
    float* f2  = (float*)(ws + WS_F2);
    float* w2  = (float*)(ws + WS_W2);
    float* cor = (float*)(ws + WS_COR);
    float* ls2 = (float*)(ws + WS_LS2);

    const int total_waves = BATCH + CNUM + BATCH;
    prep_cor_kernel<<<(total_waves + 3) / 4, 256, 0, stream>>>(
        feat, weights, label, featb, wb, f2, w2, cor);
    scale_kernel<<<1, 256, 0, stream>>>(cor, ls2);

    const int MT = (CNUM + 127) / 128;   // 79
    gemm_kernel<<<MT * (BATCH / 128), 256, 0, stream>>>(featb, wb, f2, w2, ls2, out);
}

// Round 6
// 51.062 us; speedup vs baseline: 1.9803x; 1.1959x over previous
//
#include <hip/hip_runtime.h>
#include <hip/hip_bf16.h>
#include <math.h>

#define FDIM  128
#define BATCH 4096
#define CNUM  10000

typedef __attribute__((ext_vector_type(8))) short short8;   // 8 bf16 = 4 VGPRs (MFMA A/B frag)
typedef __attribute__((ext_vector_type(4))) float f32x4;    // MFMA C/D frag / float4 store

// ---------------- ws layout (bytes) ----------------
#define WS_FEATB 0            // 4096*128 bf16  = 1048576
#define WS_WB    1048576      // 10000*128 bf16 = 2560000
#define WS_F2    3608576      // 4096 f32
#define WS_W2    3624960      // 10000 f32
#define WS_COR   3664960      // 4096 f32
#define WS_LS2   3681344      // 1 f32 (log2 of scale)

// exp(-m/1.8) = 2^(-m * C2);  C2 = 1/(1.8*ln2)
#define C2 0.80178372573096f

// async global->LDS, 16B per lane, literal size
#define GL2LDS(g, l) __builtin_amdgcn_global_load_lds(                      \
    (const __attribute__((address_space(1))) void*)(g),                     \
    (__attribute__((address_space(3))) void*)(l), 16, 0, 0)

// Kernel 1: fused prep (f32->bf16 convert + row norms) and cor gather.
__global__ void prep_cor_kernel(const float* __restrict__ feat,
                                const float* __restrict__ weights,
                                const int* __restrict__ label,
                                __hip_bfloat16* __restrict__ featb,
                                __hip_bfloat16* __restrict__ wb,
                                float* __restrict__ f2,
                                float* __restrict__ w2,
                                float* __restrict__ cor) {
    int gw   = (blockIdx.x * blockDim.x + threadIdx.x) >> 6;
    int lane = threadIdx.x & 63;
    if (gw < BATCH + CNUM) {
        const float* src;
        __hip_bfloat16* dst;
        float* nrm;
        if (gw < BATCH) { src = feat    + (size_t)gw * FDIM; dst = featb + (size_t)gw * FDIM; nrm = f2 + gw; }
        else            { int r = gw - BATCH;
                          src = weights + (size_t)r  * FDIM; dst = wb    + (size_t)r  * FDIM; nrm = w2 + r; }
        float2 v = ((const float2*)src)[lane];
        __hip_bfloat162 b2;
        b2.x = __float2bfloat16(v.x);
        b2.y = __float2bfloat16(v.y);
        ((__hip_bfloat162*)dst)[lane] = b2;
        float ss = v.x * v.x + v.y * v.y;
        #pragma unroll
        for (int off = 32; off; off >>= 1) ss += __shfl_down(ss, off, 64);
        if (lane == 0) *nrm = ss;
    } else {
        int s = gw - (BATCH + CNUM);
        if (s >= BATCH) return;
        int lab = label[s];
        float2 f = ((const float2*)(feat    + (size_t)s   * FDIM))[lane];
        float2 w = ((const float2*)(weights + (size_t)lab * FDIM))[lane];
        float dx = f.x - w.x, dy = f.y - w.y;
        float ss = dx * dx + dy * dy;
        #pragma unroll
        for (int off = 32; off; off >>= 1) ss += __shfl_down(ss, off, 64);
        if (lane == 0) cor[s] = __expf(-ss * (1.0f / 1.8f));
    }
}

// Kernel 2: deterministic reduction of cor -> ls2 = log2(log(C-1)/max(mean,0.5)).
__global__ void scale_kernel(const float* __restrict__ cor, float* __restrict__ ls2) {
    __shared__ float red[4];
    int t = threadIdx.x;
    float s = 0.0f;
    #pragma unroll
    for (int i = 0; i < BATCH / 256; i++) s += cor[t + i * 256];
    #pragma unroll
    for (int off = 32; off; off >>= 1) s += __shfl_down(s, off, 64);
    if ((t & 63) == 0) red[t >> 6] = s;
    __syncthreads();
    if (t == 0) {
        float avg = (red[0] + red[1] + red[2] + red[3]) * (1.0f / BATCH);
        avg = fmaxf(avg, 0.5f);
        *ls2 = log2f(logf((float)(CNUM - 1)) / avg);
    }
}

// Kernel 3: persistent double-buffered band-sweep GEMM + fused epilogue.
// 256 blocks (1/CU) x 512 threads (8 waves). Block = band (256 batch rows,
// bx&15) x class-group (5 tiles of 128 classes, bx>>4; 16*5*128 = 10240 >=
// 10000, tail masked). B-band (featb, 64KB) staged ONCE, B-fragments then
// hoisted to VGPRs for the whole sweep. A (wb) double-buffered 2x32KB.
// All LDS chunk-XOR-swizzled (chunk ^= row&7) via pre-swizzled global source
// (linear LDS dest) + same XOR on ds_read.
// Wave = 64 classes x 64 batch: aoff=(wid&1)*64, boff=(wid>>1)*64, acc[4][4].
// Per iter: 4 GL2LDS prefetch, 16 a-ds_reads, 64 MFMA, 64 exp2, 16 f32x4
// stores, then s_waitcnt vmcnt(16) + raw s_barrier: retires the prefetch
// (+w4 loads) but leaves this tile's 16 stores in flight under the next
// tile's compute -> continuous HBM write stream.
// C/D: col=lane&15 -> batch row, row=kh*4+reg -> class => lane f32x4 = 4
// consecutive classes of one output row -> dwordx4 store.
__launch_bounds__(512, 2)
__global__ void gemm_kernel(const __hip_bfloat16* __restrict__ featb,
                            const __hip_bfloat16* __restrict__ wb,
                            const float* __restrict__ f2,
                            const float* __restrict__ w2,
                            const float* __restrict__ ls2_p,
                            float* __restrict__ out) {
    __shared__ __align__(16) char ldsA[65536];   // 2 x (128 x 256B) double buffer
    __shared__ __align__(16) char ldsB[65536];   // 256 x 256B, persistent

    int bx   = blockIdx.x;
    int band = bx & 15;            // 16 bands x 256 batch rows
    int cg   = bx >> 4;            // 16 class-groups x 5 tiles
    int tid  = threadIdx.x;
    int wid  = tid >> 6;
    int lane = tid & 63;
    int r16  = lane & 15;
    int kh   = lane >> 4;
    int aoff = (wid & 1) * 64;     // class half within 128-tile
    int boff = (wid >> 1) * 64;    // batch quarter within 256-band
    int t0   = cg * 5;

    const char* Ab = (const char*)wb;
    const char* Bb = (const char*)featb;

    // ---- prologue staging: B band (64KB, 8 passes) + A tile t0 (32KB, 4) ----
    #pragma unroll
    for (int p = 0; p < 8; ++p) {
        int idx = tid + p * 512;
        int row = idx >> 4, chk = idx & 15;
        int grow = band * 256 + row;
        GL2LDS(Bb + (size_t)grow * 256 + (chk ^ (row & 7)) * 16, ldsB + idx * 16);
    }
    #pragma unroll
    for (int p = 0; p < 4; ++p) {
        int idx = tid + p * 512;
        int row = idx >> 4, chk = idx & 15;
        int gc = t0 * 128 + row; gc = gc < CNUM ? gc : CNUM - 1;
        GL2LDS(Ab + (size_t)gc * 256 + (chk ^ (row & 7)) * 16, ldsA + idx * 16);
    }
    __syncthreads();   // full drain once

    float ls2 = *ls2_p;
    float f2n[4];
    #pragma unroll
    for (int n = 0; n < 4; ++n) f2n[n] = f2[band * 256 + boff + n * 16 + r16];

    // ---- hoist B fragments to VGPR for the whole sweep ----
    short8 bfrag[4][4];
    #pragma unroll
    for (int kk = 0; kk < 4; ++kk)
        #pragma unroll
        for (int n = 0; n < 4; ++n) {
            int row = boff + n * 16 + r16;
            int c = (kk * 4 + kh) ^ (row & 7);
            bfrag[kk][n] = *(const short8*)(ldsB + row * 256 + c * 16);
        }

    #pragma unroll
    for (int it = 0; it < 5; ++it) {
        int t = t0 + it;
        int cur = it & 1;

        // prefetch next A tile into the other buffer (read in it-1, barrier-safe)
        if (it < 4) {
            #pragma unroll
            for (int p = 0; p < 4; ++p) {
                int idx = tid + p * 512;
                int row = idx >> 4, chk = idx & 15;
                int gc = (t + 1) * 128 + row; gc = gc < CNUM ? gc : CNUM - 1;
                GL2LDS(Ab + (size_t)gc * 256 + (chk ^ (row & 7)) * 16,
                       ldsA + (cur ^ 1) * 32768 + idx * 16);
            }
        }

        // ---- compute from current buffer ----
        const char* Abuf = ldsA + cur * 32768;
        f32x4 acc[4][4];
        #pragma unroll
        for (int m = 0; m < 4; ++m)
            #pragma unroll
            for (int n = 0; n < 4; ++n) acc[m][n] = (f32x4){0.f, 0.f, 0.f, 0.f};

        #pragma unroll
        for (int kk = 0; kk < 4; ++kk) {
            short8 a[4];
            #pragma unroll
            for (int m = 0; m < 4; ++m) {
                int row = aoff + m * 16 + r16;
                int c = (kk * 4 + kh) ^ (row & 7);
                a[m] = *(const short8*)(Abuf + row * 256 + c * 16);
            }
            #pragma unroll
            for (int m = 0; m < 4; ++m)
                #pragma unroll
                for (int n = 0; n < 4; ++n)
                    acc[m][n] = __builtin_amdgcn_mfma_f32_16x16x32_bf16(a[m], bfrag[kk][n], acc[m][n], 0, 0, 0);
        }

        // ---- epilogue: w4 loads first, then compute+store ----
        int mbase = t * 128 + aoff;
        f32x4 w4[4];
        bool  ok[4];
        #pragma unroll
        for (int m = 0; m < 4; ++m) {
            int cm0 = mbase + m * 16 + kh * 4;
            ok[m] = cm0 < CNUM;                  // cm0,CNUM % 4 == 0 -> no straddle
            w4[m] = *(const f32x4*)(w2 + (ok[m] ? cm0 : 0));
        }
        #pragma unroll
        for (int m = 0; m < 4; ++m) {
            int cm0 = mbase + m * 16 + kh * 4;
            #pragma unroll
            for (int n = 0; n < 4; ++n) {
                f32x4 v;
                #pragma unroll
                for (int r = 0; r < 4; ++r) {
                    float mt2 = fmaf(-2.0f, acc[m][n][r], f2n[n] + w4[m][r]);
                    mt2 = fmaxf(mt2, 0.0f);
                    v[r] = exp2f(fmaf(mt2, -C2, ls2));
                }
                if (ok[m]) {
                    size_t rg = (size_t)(band * 256 + boff + n * 16 + r16);
                    *(f32x4*)(out + rg * CNUM + cm0) = v;
                }
            }
        }

        // counted-vmcnt barrier: retire prefetch GL2LDS + w4 loads (older),
        // keep this tile's 16 stores (newest) in flight under next compute.
        asm volatile("s_waitcnt vmcnt(16)" ::: "memory");
        __builtin_amdgcn_sched_barrier(0);
        __builtin_amdgcn_s_barrier();
    }
}

extern "C" void kernel_launch(void* const* d_in, const int* in_sizes, int n_in,
                              void* d_out, int out_size, void* d_ws, size_t ws_size,
                              hipStream_t stream) {
    (void)in_sizes; (void)n_in; (void)out_size; (void)ws_size;
    const float* feat    = (const float*)d_in[0];
    const float* weights = (const float*)d_in[1];
    const int*   label   = (const int*)d_in[2];
    float* out = (float*)d_out;
    char*  ws  = (char*)d_ws;

    __hip_bfloat16* featb = (__hip_bfloat16*)(ws + WS_FEATB);
    __hip_bfloat16* wb    = (__hip_bfloat16*)(ws + WS_WB);
    float* f2  = (float*)(ws + WS_F2);
    float* w2  = (float*)(ws + WS_W2);
    float* cor = (float*)(ws + WS_COR);
    float* ls2 = (float*)(ws + WS_LS2);

    const int total_waves = BATCH + CNUM + BATCH;
    prep_cor_kernel<<<(total_waves + 3) / 4, 256, 0, stream>>>(
        feat, weights, label, featb, wb, f2, w2, cor);
    scale_kernel<<<1, 256, 0, stream>>>(cor, ls2);

    gemm_kernel<<<256, 512, 0, stream>>>(featb, wb, f2, w2, ls2, out);
}

// Round 7
// 49.683 us; speedup vs baseline: 2.0352x; 1.0278x over previous
//
#include <hip/hip_runtime.h>
#include <hip/hip_bf16.h>
#include <math.h>

#define FDIM  128
#define BATCH 4096
#define CNUM  10000

typedef __attribute__((ext_vector_type(8))) short short8;   // 8 bf16 = 4 VGPRs (MFMA A/B frag)
typedef __attribute__((ext_vector_type(4))) float f32x4;    // MFMA C/D frag / float4 store

// ---------------- ws layout (bytes) ----------------
#define WS_FEATB 0            // 4096*128 bf16  = 1048576
#define WS_WB    1048576      // 10000*128 bf16 = 2560000
#define WS_F2    3608576      // 4096 f32
#define WS_W2    3624960      // 10000 f32
#define WS_COR   3664960      // 4096 f32
#define WS_LS2   3681344      // 1 f32 (log2 of scale)

// exp(-m/1.8) = 2^(-m * C2);  C2 = 1/(1.8*ln2)
#define C2 0.80178372573096f

// async global->LDS, 16B per lane, literal size
#define GL2LDS(g, l) __builtin_amdgcn_global_load_lds(                      \
    (const __attribute__((address_space(1))) void*)(g),                     \
    (__attribute__((address_space(3))) void*)(l), 16, 0, 0)

// Kernel 1: fused prep (f32->bf16 convert + row norms) and cor gather.
__global__ void prep_cor_kernel(const float* __restrict__ feat,
                                const float* __restrict__ weights,
                                const int* __restrict__ label,
                                __hip_bfloat16* __restrict__ featb,
                                __hip_bfloat16* __restrict__ wb,
                                float* __restrict__ f2,
                                float* __restrict__ w2,
                                float* __restrict__ cor) {
    int gw   = (blockIdx.x * blockDim.x + threadIdx.x) >> 6;
    int lane = threadIdx.x & 63;
    if (gw < BATCH + CNUM) {
        const float* src;
        __hip_bfloat16* dst;
        float* nrm;
        if (gw < BATCH) { src = feat    + (size_t)gw * FDIM; dst = featb + (size_t)gw * FDIM; nrm = f2 + gw; }
        else            { int r = gw - BATCH;
                          src = weights + (size_t)r  * FDIM; dst = wb    + (size_t)r  * FDIM; nrm = w2 + r; }
        float2 v = ((const float2*)src)[lane];
        __hip_bfloat162 b2;
        b2.x = __float2bfloat16(v.x);
        b2.y = __float2bfloat16(v.y);
        ((__hip_bfloat162*)dst)[lane] = b2;
        float ss = v.x * v.x + v.y * v.y;
        #pragma unroll
        for (int off = 32; off; off >>= 1) ss += __shfl_down(ss, off, 64);
        if (lane == 0) *nrm = ss;
    } else {
        int s = gw - (BATCH + CNUM);
        if (s >= BATCH) return;
        int lab = label[s];
        float2 f = ((const float2*)(feat    + (size_t)s   * FDIM))[lane];
        float2 w = ((const float2*)(weights + (size_t)lab * FDIM))[lane];
        float dx = f.x - w.x, dy = f.y - w.y;
        float ss = dx * dx + dy * dy;
        #pragma unroll
        for (int off = 32; off; off >>= 1) ss += __shfl_down(ss, off, 64);
        if (lane == 0) cor[s] = __expf(-ss * (1.0f / 1.8f));
    }
}

// Kernel 2: deterministic reduction of cor -> ls2 = log2(log(C-1)/max(mean,0.5)).
__global__ void scale_kernel(const float* __restrict__ cor, float* __restrict__ ls2) {
    __shared__ float red[4];
    int t = threadIdx.x;
    float s = 0.0f;
    #pragma unroll
    for (int i = 0; i < BATCH / 256; i++) s += cor[t + i * 256];
    #pragma unroll
    for (int off = 32; off; off >>= 1) s += __shfl_down(s, off, 64);
    if ((t & 63) == 0) red[t >> 6] = s;
    __syncthreads();
    if (t == 0) {
        float avg = (red[0] + red[1] + red[2] + red[3]) * (1.0f / BATCH);
        avg = fmaxf(avg, 0.5f);
        *ls2 = log2f(logf((float)(CNUM - 1)) / avg);
    }
}

// Kernel 3: persistent double-buffered band-sweep GEMM, 2 blocks/CU.
// 512 blocks x 512 threads (8 waves). Block = band (128 batch rows, bx&31)
// x class-group (5 tiles of 128 classes, bx>>5). LDS = ONE 64KB pair:
// B band (32KB) staged into buf1, hoisted to VGPRs, then buf1 joins the A
// double-buffer. 64KB/block -> 2 blocks resident/CU (16 waves/CU): one
// block computes/stores while the other sits at its barrier.
// Chunk-XOR swizzle (chunk ^= row&7) via pre-swizzled global source + same
// XOR on ds_read. Wave = 64 classes (aoff=(wid&1)*64) x 32 rows
// (boff=(wid>>1)*32): bfrag[4][2], acc[4][2].
// Per iter/wave: 4 GL2LDS prefetch, 16 a-ds_reads, 32 MFMA, 4 w4 loads,
// 8 f32x4 stores, then s_waitcnt vmcnt(12) + s_barrier: retires exactly
// through the prefetch, keeps all 8 stores in flight under next compute.
__launch_bounds__(512, 4)
__global__ void gemm_kernel(const __hip_bfloat16* __restrict__ featb,
                            const __hip_bfloat16* __restrict__ wb,
                            const float* __restrict__ f2,
                            const float* __restrict__ w2,
                            const float* __restrict__ ls2_p,
                            float* __restrict__ out) {
    __shared__ __align__(16) char lds[65536];    // buf0 | buf1 (32KB each)

    int bx   = blockIdx.x;
    int band = bx & 31;            // 32 bands x 128 batch rows
    int cg   = bx >> 5;            // 16 class-groups x 5 tiles
    int tid  = threadIdx.x;
    int wid  = tid >> 6;
    int lane = tid & 63;
    int r16  = lane & 15;
    int kh   = lane >> 4;
    int aoff = (wid & 1) * 64;     // class half within 128-tile
    int boff = (wid >> 1) * 32;    // row quarter within 128-band
    int t0   = cg * 5;

    const char* Ab = (const char*)wb;
    const char* Bb = (const char*)featb;

    // ---- prologue: B band (32KB) -> buf1, tile t0 (32KB) -> buf0 ----
    #pragma unroll
    for (int p = 0; p < 4; ++p) {
        int idx = tid + p * 512;
        int row = idx >> 4, chk = idx & 15;
        int grow = band * 128 + row;
        GL2LDS(Bb + (size_t)grow * 256 + (chk ^ (row & 7)) * 16, lds + 32768 + idx * 16);
    }
    #pragma unroll
    for (int p = 0; p < 4; ++p) {
        int idx = tid + p * 512;
        int row = idx >> 4, chk = idx & 15;
        int gc = t0 * 128 + row; gc = gc < CNUM ? gc : CNUM - 1;
        GL2LDS(Ab + (size_t)gc * 256 + (chk ^ (row & 7)) * 16, lds + idx * 16);
    }
    float ls2 = *ls2_p;
    float f2n[2];
    #pragma unroll
    for (int n = 0; n < 2; ++n) f2n[n] = f2[band * 128 + boff + n * 16 + r16];
    __syncthreads();                               // full drain once

    // ---- hoist B fragments to VGPR (from buf1) ----
    short8 bfrag[4][2];
    #pragma unroll
    for (int kk = 0; kk < 4; ++kk)
        #pragma unroll
        for (int n = 0; n < 2; ++n) {
            int row = boff + n * 16 + r16;
            int c = (kk * 4 + kh) ^ (row & 7);
            bfrag[kk][n] = *(const short8*)(lds + 32768 + row * 256 + c * 16);
        }
    __syncthreads();   // bfrag reads complete before buf1 is overwritten

    #pragma unroll
    for (int it = 0; it < 5; ++it) {
        int t = t0 + it;
        int cur = it & 1;

        // prefetch next A tile into the other buffer
        if (it < 4) {
            #pragma unroll
            for (int p = 0; p < 4; ++p) {
                int idx = tid + p * 512;
                int row = idx >> 4, chk = idx & 15;
                int gc = (t + 1) * 128 + row; gc = gc < CNUM ? gc : CNUM - 1;
                GL2LDS(Ab + (size_t)gc * 256 + (chk ^ (row & 7)) * 16,
                       lds + (cur ^ 1) * 32768 + idx * 16);
            }
        }

        // ---- compute from current buffer ----
        const char* Abuf = lds + cur * 32768;
        f32x4 acc[4][2];
        #pragma unroll
        for (int m = 0; m < 4; ++m)
            #pragma unroll
            for (int n = 0; n < 2; ++n) acc[m][n] = (f32x4){0.f, 0.f, 0.f, 0.f};

        #pragma unroll
        for (int kk = 0; kk < 4; ++kk) {
            short8 a[4];
            #pragma unroll
            for (int m = 0; m < 4; ++m) {
                int row = aoff + m * 16 + r16;
                int c = (kk * 4 + kh) ^ (row & 7);
                a[m] = *(const short8*)(Abuf + row * 256 + c * 16);
            }
            #pragma unroll
            for (int m = 0; m < 4; ++m)
                #pragma unroll
                for (int n = 0; n < 2; ++n)
                    acc[m][n] = __builtin_amdgcn_mfma_f32_16x16x32_bf16(a[m], bfrag[kk][n], acc[m][n], 0, 0, 0);
        }

        // ---- epilogue per-m (w4 just-in-time, keeps VGPR low) ----
        int mbase = t * 128 + aoff;
        #pragma unroll
        for (int m = 0; m < 4; ++m) {
            int cm0 = mbase + m * 16 + kh * 4;     // first of 4 consecutive classes
            bool ok = cm0 < CNUM;                   // cm0,CNUM % 4 == 0 -> no straddle
            f32x4 w4 = *(const f32x4*)(w2 + (ok ? cm0 : 0));
            #pragma unroll
            for (int n = 0; n < 2; ++n) {
                f32x4 v;
                #pragma unroll
                for (int r = 0; r < 4; ++r) {
                    float mt2 = fmaf(-2.0f, acc[m][n][r], f2n[n] + w4[r]);
                    mt2 = fmaxf(mt2, 0.0f);
                    v[r] = exp2f(fmaf(mt2, -C2, ls2));
                }
                if (ok) {
                    size_t rg = (size_t)(band * 128 + boff + n * 16 + r16);
                    *(f32x4*)(out + rg * CNUM + cm0) = v;
                }
            }
        }

        // counted-vmcnt barrier: 4 w4 + 8 stores issued after the 4 prefetch
        // -> vmcnt(12) retires exactly through the prefetch, keeps stores
        // in flight under the next tile's compute.
        asm volatile("s_waitcnt vmcnt(12)" ::: "memory");
        __builtin_amdgcn_sched_barrier(0);
        __builtin_amdgcn_s_barrier();
    }
}

extern "C" void kernel_launch(void* const* d_in, const int* in_sizes, int n_in,
                              void* d_out, int out_size, void* d_ws, size_t ws_size,
                              hipStream_t stream) {
    (void)in_sizes; (void)n_in; (void)out_size; (void)ws_size;
    const float* feat    = (const float*)d_in[0];
    const float* weights = (const float*)d_in[1];
    const int*   label   = (const int*)d_in[2];
    float* out = (float*)d_out;
    char*  ws  = (char*)d_ws;

    __hip_bfloat16* featb = (__hip_bfloat16*)(ws + WS_FEATB);
    __hip_bfloat16* wb    = (__hip_bfloat16*)(ws + WS_WB);
    float* f2  = (float*)(ws + WS_F2);
    float* w2  = (float*)(ws + WS_W2);
    float* cor = (float*)(ws + WS_COR);
    float* ls2 = (float*)(ws + WS_LS2);

    const int total_waves = BATCH + CNUM + BATCH;
    prep_cor_kernel<<<(total_waves + 3) / 4, 256, 0, stream>>>(
        feat, weights, label, featb, wb, f2, w2, cor);
    scale_kernel<<<1, 256, 0, stream>>>(cor, ls2);

    gemm_kernel<<<512, 512, 0, stream>>>(featb, wb, f2, w2, ls2, out);
}

// Round 8
// 49.604 us; speedup vs baseline: 2.0384x; 1.0016x over previous
//
#include <hip/hip_runtime.h>
#include <hip/hip_bf16.h>
#include <math.h>

#define FDIM  128
#define BATCH 4096
#define CNUM  10000

typedef __attribute__((ext_vector_type(8))) short short8;   // 8 bf16 = 4 VGPRs (MFMA A/B frag)
typedef __attribute__((ext_vector_type(4))) float f32x4;    // MFMA C/D frag / float4 store

// ---------------- ws layout (bytes) ----------------
#define WS_FEATB 0            // 4096*128 bf16  = 1048576
#define WS_WB    1048576      // 10000*128 bf16 = 2560000
#define WS_F2    3608576      // 4096 f32
#define WS_W2    3624960      // 10000 f32
#define WS_COR   3664960      // 4096 f32

// exp(-m/1.8) = 2^(-m * C2);  C2 = 1/(1.8*ln2)
#define C2 0.80178372573096f

// async global->LDS, 16B per lane, literal size
#define GL2LDS(g, l) __builtin_amdgcn_global_load_lds(                      \
    (const __attribute__((address_space(1))) void*)(g),                     \
    (__attribute__((address_space(3))) void*)(l), 16, 0, 0)

// Kernel 1: fused prep (f32->bf16 convert + row norms) and cor gather.
__global__ void prep_cor_kernel(const float* __restrict__ feat,
                                const float* __restrict__ weights,
                                const int* __restrict__ label,
                                __hip_bfloat16* __restrict__ featb,
                                __hip_bfloat16* __restrict__ wb,
                                float* __restrict__ f2,
                                float* __restrict__ w2,
                                float* __restrict__ cor) {
    int gw   = (blockIdx.x * blockDim.x + threadIdx.x) >> 6;
    int lane = threadIdx.x & 63;
    if (gw < BATCH + CNUM) {
        const float* src;
        __hip_bfloat16* dst;
        float* nrm;
        if (gw < BATCH) { src = feat    + (size_t)gw * FDIM; dst = featb + (size_t)gw * FDIM; nrm = f2 + gw; }
        else            { int r = gw - BATCH;
                          src = weights + (size_t)r  * FDIM; dst = wb    + (size_t)r  * FDIM; nrm = w2 + r; }
        float2 v = ((const float2*)src)[lane];
        __hip_bfloat162 b2;
        b2.x = __float2bfloat16(v.x);
        b2.y = __float2bfloat16(v.y);
        ((__hip_bfloat162*)dst)[lane] = b2;
        float ss = v.x * v.x + v.y * v.y;
        #pragma unroll
        for (int off = 32; off; off >>= 1) ss += __shfl_down(ss, off, 64);
        if (lane == 0) *nrm = ss;
    } else {
        int s = gw - (BATCH + CNUM);
        if (s >= BATCH) return;
        int lab = label[s];
        float2 f = ((const float2*)(feat    + (size_t)s   * FDIM))[lane];
        float2 w = ((const float2*)(weights + (size_t)lab * FDIM))[lane];
        float dx = f.x - w.x, dy = f.y - w.y;
        float ss = dx * dx + dy * dy;
        #pragma unroll
        for (int off = 32; off; off >>= 1) ss += __shfl_down(ss, off, 64);
        if (lane == 0) cor[s] = __expf(-ss * (1.0f / 1.8f));
    }
}

// Kernel 2: persistent double-buffered band-sweep GEMM, 2 blocks/CU.
// 512 blocks x 512 threads (8 waves). Block = band (128 batch rows, bx&31)
// x class-group cg (bx>>5), sweeping INTERLEAVED tiles t = it*16 + cg
// (it=0..4): adjacent 512B column-chunks of a row are written by
// NEIGHBORING cg blocks (same XCD: bx diff 32) in the SAME iteration
// window -> straddled 128B lines (odd rows: stride 40000B = 64 mod 128)
// merge in L2 instead of double-writeback.
// B (featb) fragments loaded DIRECTLY from global (L2-resident, one-time)
// -> LDS = pure A double-buffer 2x32KB. Scale (ls2) computed in prologue
// by every block (deterministic identical reduction of cor, hidden under
// the 32KB staging wait).
// Chunk-XOR swizzle (chunk ^= row&7) via pre-swizzled global source +
// same XOR on ds_read. Wave = 64 classes (aoff=(wid&1)*64) x 32 rows
// (boff=(wid>>1)*32): bfrag[4][2], acc[4][2].
// Per iter: 4 GL2LDS prefetch (pinned first by sched_barrier), 16
// a-ds_reads, 32 MFMA, 4 w4 loads, 8 f32x4 stores, then s_waitcnt
// vmcnt(8) + s_barrier: retires everything except the 8 stores, which
// stay in flight under the next tile's compute.
__launch_bounds__(512, 4)
__global__ void gemm_kernel(const __hip_bfloat16* __restrict__ featb,
                            const __hip_bfloat16* __restrict__ wb,
                            const float* __restrict__ f2,
                            const float* __restrict__ w2,
                            const float* __restrict__ cor,
                            float* __restrict__ out) {
    __shared__ __align__(16) char lds[65536];    // A double buffer: buf0 | buf1
    __shared__ float red[8];

    int bx   = blockIdx.x;
    int band = bx & 31;            // 32 bands x 128 batch rows
    int cg   = bx >> 5;            // 16 class-groups, tiles t = it*16+cg
    int tid  = threadIdx.x;
    int wid  = tid >> 6;
    int lane = tid & 63;
    int r16  = lane & 15;
    int kh   = lane >> 4;
    int aoff = (wid & 1) * 64;     // class half within 128-tile
    int boff = (wid >> 1) * 32;    // row quarter within 128-band

    const char* Ab = (const char*)wb;

    // ---- prologue: stage tile t=cg into buf0 ----
    #pragma unroll
    for (int p = 0; p < 4; ++p) {
        int idx = tid + p * 512;
        int row = idx >> 4, chk = idx & 15;
        int gc = cg * 128 + row; gc = gc < CNUM ? gc : CNUM - 1;
        GL2LDS(Ab + (size_t)gc * 256 + (chk ^ (row & 7)) * 16, lds + idx * 16);
    }

    // ---- deterministic scale reduction (identical in every block),
    //      hidden under the staging wait ----
    {
        float s = 0.0f;
        #pragma unroll
        for (int i = 0; i < BATCH / 512; ++i) s += cor[tid + i * 512];
        #pragma unroll
        for (int off = 32; off; off >>= 1) s += __shfl_down(s, off, 64);
        if (lane == 0) red[wid] = s;
    }

    float f2n[2];
    #pragma unroll
    for (int n = 0; n < 2; ++n) f2n[n] = f2[band * 128 + boff + n * 16 + r16];

    __syncthreads();   // full drain (staging + red visible)

    float tot = 0.0f;
    #pragma unroll
    for (int i = 0; i < 8; ++i) tot += red[i];
    float avg = fmaxf(tot * (1.0f / BATCH), 0.5f);
    float ls2 = log2f(logf((float)(CNUM - 1)) / avg);

    // ---- B fragments straight from global (featb is L2-resident) ----
    const char* Bb = (const char*)featb;
    short8 bfrag[4][2];
    #pragma unroll
    for (int kk = 0; kk < 4; ++kk)
        #pragma unroll
        for (int n = 0; n < 2; ++n) {
            int row = band * 128 + boff + n * 16 + r16;
            bfrag[kk][n] = *(const short8*)(Bb + (size_t)row * 256 + kk * 64 + kh * 16);
        }

    #pragma unroll
    for (int it = 0; it < 5; ++it) {
        int t   = it * 16 + cg;        // interleaved tile index
        int cur = it & 1;

        // prefetch next tile into the other buffer (pinned before compute)
        if (it < 4) {
            int tn = t + 16;
            #pragma unroll
            for (int p = 0; p < 4; ++p) {
                int idx = tid + p * 512;
                int row = idx >> 4, chk = idx & 15;
                int gc = tn * 128 + row; gc = gc < CNUM ? gc : CNUM - 1;
                GL2LDS(Ab + (size_t)gc * 256 + (chk ^ (row & 7)) * 16,
                       lds + (cur ^ 1) * 32768 + idx * 16);
            }
        }
        __builtin_amdgcn_sched_barrier(0);   // prefetch issued before compute

        // ---- compute from current buffer ----
        const char* Abuf = lds + cur * 32768;
        f32x4 acc[4][2];
        #pragma unroll
        for (int m = 0; m < 4; ++m)
            #pragma unroll
            for (int n = 0; n < 2; ++n) acc[m][n] = (f32x4){0.f, 0.f, 0.f, 0.f};

        #pragma unroll
        for (int kk = 0; kk < 4; ++kk) {
            short8 a[4];
            #pragma unroll
            for (int m = 0; m < 4; ++m) {
                int row = aoff + m * 16 + r16;
                int c = (kk * 4 + kh) ^ (row & 7);
                a[m] = *(const short8*)(Abuf + row * 256 + c * 16);
            }
            #pragma unroll
            for (int m = 0; m < 4; ++m)
                #pragma unroll
                for (int n = 0; n < 2; ++n)
                    acc[m][n] = __builtin_amdgcn_mfma_f32_16x16x32_bf16(a[m], bfrag[kk][n], acc[m][n], 0, 0, 0);
        }

        // ---- epilogue per-m (w4 just-in-time) ----
        int mbase = t * 128 + aoff;
        #pragma unroll
        for (int m = 0; m < 4; ++m) {
            int cm0 = mbase + m * 16 + kh * 4;     // first of 4 consecutive classes
            bool ok = cm0 < CNUM;                   // cm0,CNUM % 4 == 0 -> no straddle
            f32x4 w4 = *(const f32x4*)(w2 + (ok ? cm0 : 0));
            #pragma unroll
            for (int n = 0; n < 2; ++n) {
                f32x4 v;
                #pragma unroll
                for (int r = 0; r < 4; ++r) {
                    float mt2 = fmaf(-2.0f, acc[m][n][r], f2n[n] + w4[r]);
                    mt2 = fmaxf(mt2, 0.0f);
                    v[r] = exp2f(fmaf(mt2, -C2, ls2));
                }
                if (ok) {
                    size_t rg = (size_t)(band * 128 + boff + n * 16 + r16);
                    *(f32x4*)(out + rg * CNUM + cm0) = v;
                }
            }
        }

        // counted-vmcnt barrier: retire prefetch + w4 (order-independent),
        // keep this iter's 8 stores in flight under the next compute.
        asm volatile("s_waitcnt vmcnt(8)" ::: "memory");
        __builtin_amdgcn_sched_barrier(0);
        __builtin_amdgcn_s_barrier();
    }
}

extern "C" void kernel_launch(void* const* d_in, const int* in_sizes, int n_in,
                              void* d_out, int out_size, void* d_ws, size_t ws_size,
                              hipStream_t stream) {
    (void)in_sizes; (void)n_in; (void)out_size; (void)ws_size;
    const float* feat    = (const float*)d_in[0];
    const float* weights = (const float*)d_in[1];
    const int*   label   = (const int*)d_in[2];
    float* out = (float*)d_out;
    char*  ws  = (char*)d_ws;

    __hip_bfloat16* featb = (__hip_bfloat16*)(ws + WS_FEATB);
    __hip_bfloat16* wb    = (__hip_bfloat16*)(ws + WS_WB);
    float* f2  = (float*)(ws + WS_F2);
    float* w2  = (float*)(ws + WS_W2);
    float* cor = (float*)(ws + WS_COR);

    const int total_waves = BATCH + CNUM + BATCH;
    prep_cor_kernel<<<(total_waves + 3) / 4, 256, 0, stream>>>(
        feat, weights, label, featb, wb, f2, w2, cor);

    gemm_kernel<<<512, 512, 0, stream>>>(featb, wb, f2, w2, cor, out);
}